// Round 8
// baseline (11402.586 us; speedup 1.0000x reference)
//
#include <hip/hip_runtime.h>
#include <hip/hip_fp16.h>

// GRU: T=2048, B=64, I=H=256.  out = ([T,B,H] f32, initial hx)
//
//  1) cvt_init: f32->f16 weight copies into ws, h_state := hx, write hx tail of d_out.
//  2) gi_gemm:  gi = x @ x2h_w^T + (x2h_b + h2h_b[r,z]) via f16 MFMA, f16 in ws.
//  3) gru_rec:  64 WGs (one batch element each) x 512 threads (8 waves).
//               Weight residency (R3-R7 war): VGPR allocator spills 192-reg arrays;
//               v_dot2 can't read AGPRs; hand-asm MFMA broke hazard insertion (R7,
//               absmax 0.8). Final form: BUILTIN mfma_f32_16x16x32_f16 (compiler owns
//               hazards/waits) with B-fragments class-locked to AGPRs by per-iteration
//               empty "+a" pin asms. MFMA B-operand is AV-class -> reads AGPRs in place.
//               Wave w owns gh cols [96w,96w+96): 6 col-tiles x 8 k-tiles = 48 half8
//               = 192 AGPRs; A-fragment = h broadcast from LDS (rows replicated, D row 0
//               = gh). VGPR working set ~50 -> 192+50 fits 256 (2 waves/SIMD).

typedef _Float16 half8  __attribute__((ext_vector_type(8)));
typedef float    f32x4  __attribute__((ext_vector_type(4)));

#define T_SEQ 2048
#define BATCH 64
#define HDIM  256
#define G3    768   // 3*H

__device__ __forceinline__ float sigmoid_f(float x) {
    return 1.f / (1.f + __expf(-x));
}
__device__ __forceinline__ float tanh_f(float x) {
    float e = __expf(2.f * x);
    return 1.f - 2.f / (e + 1.f);
}

// ---------------------------------------------------------------- cvt_init
__global__ void cvt_init(const float* __restrict__ x2h_w, const float* __restrict__ h2h_w,
                         const float* __restrict__ hx,
                         _Float16* __restrict__ wx16, _Float16* __restrict__ wh16,
                         float* __restrict__ hstate, float* __restrict__ out_tail) {
    int i = blockIdx.x * 256 + threadIdx.x;
    if (i < G3 * HDIM) {
        wx16[i] = (_Float16)x2h_w[i];
        wh16[i] = (_Float16)h2h_w[i];
    }
    if (i < BATCH * HDIM) {
        float v = hx[i];
        hstate[i] = v;
        out_tail[i] = v;   // second output = INITIAL hx
    }
}

// ---------------------------------------------------------------- gi_gemm
// mfma_f32_16x16x32_f16: A lane holds A[row=l&15, k=(l>>4)*8+i];
// B lane holds B[k=(l>>4)*8+i, col=l&15]; D lane holds C[row=(l>>4)*4+r, col=l&15].
// Bias: x2h_b[col] + (col<512 ? h2h_b[col] : 0).
__global__ __launch_bounds__(256) void gi_gemm(const float* __restrict__ x,
                                               const _Float16* __restrict__ wx,
                                               const float* __restrict__ bx,
                                               const float* __restrict__ bh,
                                               _Float16* __restrict__ gi,
                                               int row_base) {
    const int lane  = threadIdx.x & 63;
    const int wave  = threadIdx.x >> 6;
    const int l15   = lane & 15;
    const int kslot = lane >> 4;               // 0..3
    const int row0  = row_base + blockIdx.x * 256 + wave * 64;

    half8 a[4][8];
    #pragma unroll
    for (int s = 0; s < 4; ++s) {
        const float* xr = x + (size_t)(row0 + s * 16 + l15) * HDIM + kslot * 8;
        #pragma unroll
        for (int kt = 0; kt < 8; ++kt) {
            float4 lo = *(const float4*)(xr + kt * 32);
            float4 hi = *(const float4*)(xr + kt * 32 + 4);
            half8 v;
            v[0] = (_Float16)lo.x; v[1] = (_Float16)lo.y; v[2] = (_Float16)lo.z; v[3] = (_Float16)lo.w;
            v[4] = (_Float16)hi.x; v[5] = (_Float16)hi.y; v[6] = (_Float16)hi.z; v[7] = (_Float16)hi.w;
            a[s][kt] = v;
        }
    }

    for (int nt = 0; nt < 48; ++nt) {
        half8 b[8];
        const _Float16* wr = wx + (size_t)(nt * 16 + l15) * HDIM + kslot * 8;
        #pragma unroll
        for (int kt = 0; kt < 8; ++kt) b[kt] = *(const half8*)(wr + kt * 32);
        const int   col  = nt * 16 + l15;
        float bias = bx[col];
        if (col < 512) bias += bh[col];
        #pragma unroll
        for (int s = 0; s < 4; ++s) {
            f32x4 acc = {0.f, 0.f, 0.f, 0.f};
            #pragma unroll
            for (int kt = 0; kt < 8; ++kt)
                acc = __builtin_amdgcn_mfma_f32_16x16x32_f16(a[s][kt], b[kt], acc, 0, 0, 0);
            #pragma unroll
            for (int r = 0; r < 4; ++r) {
                int rowl = (row0 - row_base) + s * 16 + kslot * 4 + r;
                gi[(size_t)rowl * G3 + col] = (_Float16)(acc[r] + bias);
            }
        }
    }
}

// ---------------------------------------------------------------- gru_rec
__global__ __launch_bounds__(512, 2) void gru_rec(const _Float16* __restrict__ gi,
                                                  const _Float16* __restrict__ wh,
                                                  const float* __restrict__ bh,
                                                  const float* __restrict__ hx,
                                                  float* __restrict__ hstate,
                                                  float* __restrict__ out,
                                                  int t_start, int t_len) {
    __shared__ __align__(16) _Float16 hbuf[2][HDIM];
    __shared__ float ghsm[G3];

    const int tid   = threadIdx.x;
    const int lane  = tid & 63;
    const int w     = tid >> 6;           // wave 0..7, owns cols [96w, 96w+96)
    const int l15   = lane & 15;
    const int kslot = lane >> 4;          // 0..3
    const int b     = blockIdx.x;

    // B-fragments: wb[t6][kt] lane holds Wh[96w+16*t6+l15, kt*32+kslot*8 + 0..7]
    // 48 half8 = 192 registers, class-locked to AGPR by the per-iteration pins.
    half8 wb[6][8];
    #pragma unroll
    for (int t6 = 0; t6 < 6; ++t6) {
        const _Float16* row = wh + (size_t)(w * 96 + t6 * 16 + l15) * HDIM + kslot * 8;
        #pragma unroll
        for (int kt = 0; kt < 8; ++kt)
            wb[t6][kt] = *(const half8*)(row + kt * 32);
    }

    const int j = tid & 255;              // gate index (threads 0..255 do gates)
    const float bn = bh[j + 512];         // r/z h2h biases folded into gi

    float h_old = 0.f;
    if (tid < HDIM) {
        h_old = (t_start == 0) ? hx[b * HDIM + tid] : hstate[b * HDIM + tid];
        hbuf[0][tid] = (_Float16)h_old;
    }
    __syncthreads();

    const size_t STEP  = (size_t)BATCH * G3;
    const size_t OSTEP = (size_t)BATCH * HDIM;
    const _Float16* gp = gi + (size_t)b * G3 + j;
    float* outp = out + ((size_t)t_start * BATCH + b) * HDIM + j;

    // 1-deep gi prefetch (current step), threads < 256 only
    float cr = 0.f, cz = 0.f, cn = 0.f;
    if (tid < 256) {
        cr = (float)gp[0];
        cz = (float)gp[256];
        cn = (float)gp[512];
    }

    int p = 0;
    for (int tt = 0; tt < t_len; ++tt) {
        // Pin all 48 weight quads in AGPRs (class forced, remat illegal).
        asm volatile("" : "+a"(wb[0][0]), "+a"(wb[0][1]), "+a"(wb[0][2]), "+a"(wb[0][3]),
                          "+a"(wb[0][4]), "+a"(wb[0][5]), "+a"(wb[0][6]), "+a"(wb[0][7]));
        asm volatile("" : "+a"(wb[1][0]), "+a"(wb[1][1]), "+a"(wb[1][2]), "+a"(wb[1][3]),
                          "+a"(wb[1][4]), "+a"(wb[1][5]), "+a"(wb[1][6]), "+a"(wb[1][7]));
        asm volatile("" : "+a"(wb[2][0]), "+a"(wb[2][1]), "+a"(wb[2][2]), "+a"(wb[2][3]),
                          "+a"(wb[2][4]), "+a"(wb[2][5]), "+a"(wb[2][6]), "+a"(wb[2][7]));
        asm volatile("" : "+a"(wb[3][0]), "+a"(wb[3][1]), "+a"(wb[3][2]), "+a"(wb[3][3]),
                          "+a"(wb[3][4]), "+a"(wb[3][5]), "+a"(wb[3][6]), "+a"(wb[3][7]));
        asm volatile("" : "+a"(wb[4][0]), "+a"(wb[4][1]), "+a"(wb[4][2]), "+a"(wb[4][3]),
                          "+a"(wb[4][4]), "+a"(wb[4][5]), "+a"(wb[4][6]), "+a"(wb[4][7]));
        asm volatile("" : "+a"(wb[5][0]), "+a"(wb[5][1]), "+a"(wb[5][2]), "+a"(wb[5][3]),
                          "+a"(wb[5][4]), "+a"(wb[5][5]), "+a"(wb[5][6]), "+a"(wb[5][7]));

        // MFMA sweep: 2 groups x 3 col-tiles x 8 k-tiles (builtin -> compiler hazards).
        // A-frag: h broadcast, half8 at hbuf[p] halfword offset kt*32+kslot*8.
        const half8* hp8 = (const half8*)hbuf[p];
        #pragma unroll
        for (int g = 0; g < 2; ++g) {
            f32x4 a0 = {0.f, 0.f, 0.f, 0.f};
            f32x4 a1 = {0.f, 0.f, 0.f, 0.f};
            f32x4 a2 = {0.f, 0.f, 0.f, 0.f};
            half8 af[4];
            #pragma unroll
            for (int k = 0; k < 4; ++k) af[k] = hp8[k * 4 + kslot];
            #pragma unroll
            for (int kt = 0; kt < 8; ++kt) {
                const half8 av = af[kt & 3];
                if (kt + 4 < 8) af[kt & 3] = hp8[(kt + 4) * 4 + kslot];
                a0 = __builtin_amdgcn_mfma_f32_16x16x32_f16(av, wb[g * 3 + 0][kt], a0, 0, 0, 0);
                a1 = __builtin_amdgcn_mfma_f32_16x16x32_f16(av, wb[g * 3 + 1][kt], a1, 0, 0, 0);
                a2 = __builtin_amdgcn_mfma_f32_16x16x32_f16(av, wb[g * 3 + 2][kt], a2, 0, 0, 0);
            }
            if (lane < 16) {   // D rows replicated: gh[col] = row-0 value = a*[0]
                ghsm[w * 96 + (g * 3 + 0) * 16 + lane] = a0[0];
                ghsm[w * 96 + (g * 3 + 1) * 16 + lane] = a1[0];
                ghsm[w * 96 + (g * 3 + 2) * 16 + lane] = a2[0];
            }
        }
        __syncthreads();

        if (tid < 256) {
            const float ur = cr, uz = cz, un = cn;
            if (tt + 1 < t_len) {
                const _Float16* gn2 = gp + STEP;
                cr = (float)gn2[0];
                cz = (float)gn2[256];
                cn = (float)gn2[512];
            }
            float r = sigmoid_f(ghsm[j] + ur);
            float z = sigmoid_f(ghsm[j + 256] + uz);
            float n = tanh_f(un + r * (ghsm[j + 512] + bn));
            float hnew = (1.f - z) * n + z * h_old;
            *outp = hnew;
            h_old = hnew;
            hbuf[p ^ 1][j] = (_Float16)hnew;
        }
        gp += STEP;
        outp += OSTEP;
        __syncthreads();
        p ^= 1;
    }
    if (tid < 256) hstate[b * HDIM + tid] = h_old;
}

// ---------------------------------------------------------------- host
extern "C" void kernel_launch(void* const* d_in, const int* in_sizes, int n_in,
                              void* d_out, int out_size, void* d_ws, size_t ws_size,
                              hipStream_t stream) {
    const float* x     = (const float*)d_in[0];
    const float* hx    = (const float*)d_in[1];
    const float* x2h_w = (const float*)d_in[2];
    const float* h2h_w = (const float*)d_in[3];
    const float* x2h_b = (const float*)d_in[4];
    const float* h2h_b = (const float*)d_in[5];
    float* out = (float*)d_out;

    char* ws = (char*)d_ws;
    _Float16* wx16   = (_Float16*)ws;                    // 393216 B
    _Float16* wh16   = (_Float16*)(ws + 393216);         // 393216 B
    float*    hstate = (float*)(ws + 786432);            // 65536 B
    _Float16* gi     = (_Float16*)(ws + 851968);

    size_t gi_cap_elems = (ws_size > 851968) ? (ws_size - 851968) / 2 : 0;
    int CT = T_SEQ;
    while ((size_t)CT * BATCH * G3 > gi_cap_elems && CT > 64) CT >>= 1;

    cvt_init<<<768, 256, 0, stream>>>(x2h_w, h2h_w, hx, wx16, wh16, hstate,
                                      out + (size_t)T_SEQ * BATCH * HDIM);

    for (int t0 = 0; t0 < T_SEQ; t0 += CT) {
        int rows = CT * BATCH;
        gi_gemm<<<rows / 256, 256, 0, stream>>>(x, wx16, x2h_b, h2h_b, gi, t0 * BATCH);
        gru_rec<<<BATCH, 512, 0, stream>>>(gi, wh16, h2h_b, hx, hstate, out, t0, CT);
    }
}

// Round 9
// 2752.742 us; speedup vs baseline: 4.1423x; 4.1423x over previous
//
#include <hip/hip_runtime.h>
#include <hip/hip_fp16.h>

// GRU: T=2048, B=64, I=H=256.  out = ([T,B,H] f32, initial hx)
//
//  1) cvt_init: f32->f16 weight copies into ws, h_state := hx, write hx tail of d_out.
//  2) gi_gemm:  gi = x @ x2h_w^T + (x2h_b + h2h_b[r,z]) via f16 MFMA, f16 in ws.
//  3) gru_rec:  64 WGs (one batch element) x 1024 threads, K-SPLIT BY 4.
//               Residency war history: allocator keeps only ~85 regs of a pinned
//               array (R1/R3/R4/R5 all consistent); 192-reg arrays spill to scratch
//               (L2-bound 2.4 ms); AGPR path has no VALU-readable dot (R6) and the
//               builtin-MFMA/AGPR mix generates copy storms (R8 11 ms). Strategy:
//               shrink per-thread weight block to 24 quads = 96 regs (just above the
//               keep threshold; partial spill is cheap), per-iter pin to forbid remat.
//               Thread (q=tid>>8, j=tid&255) owns K-slice [64q,64q+64) of h2h_w rows
//               {j, j+256, j+512}. 4-way psum exchange in LDS, gates on q==0 threads,
//               2 barriers/step. VALU floor 768 cyc/SIMD/step, 4 waves/SIMD for TLP.

typedef _Float16 half2v __attribute__((ext_vector_type(2)));
typedef _Float16 half8  __attribute__((ext_vector_type(8)));
typedef float    f32x4  __attribute__((ext_vector_type(4)));
typedef unsigned int uint4v __attribute__((ext_vector_type(4)));

#define T_SEQ 2048
#define BATCH 64
#define HDIM  256
#define G3    768   // 3*H

__device__ __forceinline__ half2v u2h(unsigned int u) {
    union { unsigned int u; half2v h; } c; c.u = u; return c.h;
}

__device__ __forceinline__ float fdot2(half2v a, half2v b, float c) {
#if __has_builtin(__builtin_amdgcn_fdot2)
    return __builtin_amdgcn_fdot2(a, b, c, false);
#else
    return c + (float)a[0] * (float)b[0] + (float)a[1] * (float)b[1];
#endif
}

__device__ __forceinline__ float sigmoid_f(float x) {
    return 1.f / (1.f + __expf(-x));
}
__device__ __forceinline__ float tanh_f(float x) {
    float e = __expf(2.f * x);
    return 1.f - 2.f / (e + 1.f);
}

// ---------------------------------------------------------------- cvt_init
__global__ void cvt_init(const float* __restrict__ x2h_w, const float* __restrict__ h2h_w,
                         const float* __restrict__ hx,
                         _Float16* __restrict__ wx16, _Float16* __restrict__ wh16,
                         float* __restrict__ hstate, float* __restrict__ out_tail) {
    int i = blockIdx.x * 256 + threadIdx.x;
    if (i < G3 * HDIM) {
        wx16[i] = (_Float16)x2h_w[i];
        wh16[i] = (_Float16)h2h_w[i];
    }
    if (i < BATCH * HDIM) {
        float v = hx[i];
        hstate[i] = v;
        out_tail[i] = v;   // second output = INITIAL hx
    }
}

// ---------------------------------------------------------------- gi_gemm
// mfma_f32_16x16x32_f16: A lane holds A[row=l&15, k=(l>>4)*8+i];
// B lane holds B[k=(l>>4)*8+i, col=l&15]; D lane holds C[row=(l>>4)*4+r, col=l&15].
// Bias: x2h_b[col] + (col<512 ? h2h_b[col] : 0).
__global__ __launch_bounds__(256) void gi_gemm(const float* __restrict__ x,
                                               const _Float16* __restrict__ wx,
                                               const float* __restrict__ bx,
                                               const float* __restrict__ bh,
                                               _Float16* __restrict__ gi,
                                               int row_base) {
    const int lane  = threadIdx.x & 63;
    const int wave  = threadIdx.x >> 6;
    const int l15   = lane & 15;
    const int kslot = lane >> 4;               // 0..3
    const int row0  = row_base + blockIdx.x * 256 + wave * 64;

    half8 a[4][8];
    #pragma unroll
    for (int s = 0; s < 4; ++s) {
        const float* xr = x + (size_t)(row0 + s * 16 + l15) * HDIM + kslot * 8;
        #pragma unroll
        for (int kt = 0; kt < 8; ++kt) {
            float4 lo = *(const float4*)(xr + kt * 32);
            float4 hi = *(const float4*)(xr + kt * 32 + 4);
            half8 v;
            v[0] = (_Float16)lo.x; v[1] = (_Float16)lo.y; v[2] = (_Float16)lo.z; v[3] = (_Float16)lo.w;
            v[4] = (_Float16)hi.x; v[5] = (_Float16)hi.y; v[6] = (_Float16)hi.z; v[7] = (_Float16)hi.w;
            a[s][kt] = v;
        }
    }

    for (int nt = 0; nt < 48; ++nt) {
        half8 b[8];
        const _Float16* wr = wx + (size_t)(nt * 16 + l15) * HDIM + kslot * 8;
        #pragma unroll
        for (int kt = 0; kt < 8; ++kt) b[kt] = *(const half8*)(wr + kt * 32);
        const int   col  = nt * 16 + l15;
        float bias = bx[col];
        if (col < 512) bias += bh[col];
        #pragma unroll
        for (int s = 0; s < 4; ++s) {
            f32x4 acc = {0.f, 0.f, 0.f, 0.f};
            #pragma unroll
            for (int kt = 0; kt < 8; ++kt)
                acc = __builtin_amdgcn_mfma_f32_16x16x32_f16(a[s][kt], b[kt], acc, 0, 0, 0);
            #pragma unroll
            for (int r = 0; r < 4; ++r) {
                int rowl = (row0 - row_base) + s * 16 + kslot * 4 + r;
                gi[(size_t)rowl * G3 + col] = (_Float16)(acc[r] + bias);
            }
        }
    }
}

// ---------------------------------------------------------------- gru_rec
// 64 WGs x 1024 threads. K-split-4: thread (q=tid>>8, j=tid&255) owns the
// quarter-K slices of h2h_w rows j / j+256 / j+512 -> 24 quads = 96 registers.
__global__ __launch_bounds__(1024, 4) void gru_rec(const _Float16* __restrict__ gi,
                                                   const _Float16* __restrict__ wh,
                                                   const float* __restrict__ bh,
                                                   const float* __restrict__ hx,
                                                   float* __restrict__ hstate,
                                                   float* __restrict__ out,
                                                   int t_start, int t_len) {
    __shared__ __align__(16) _Float16 hbuf[2][HDIM];
    __shared__ float psum[3][3][HDIM];   // [q-1][gate][j]

    const int tid = threadIdx.x;
    const int q   = tid >> 8;            // 0..3 : K-slice [64q, 64q+64)
    const int j   = tid & 255;
    const int b   = blockIdx.x;

    // 3 quarter-rows -> 24 x uint4v = 96 VGPRs (inside the allocator's keep zone)
    uint4v wr[8], wz[8], wn[8];
    {
        const uint4v* pr = (const uint4v*)(wh + (size_t)j * HDIM + q * 64);
        const uint4v* pz = (const uint4v*)(wh + (size_t)(j + 256) * HDIM + q * 64);
        const uint4v* pn = (const uint4v*)(wh + (size_t)(j + 512) * HDIM + q * 64);
        #pragma unroll
        for (int i = 0; i < 8; ++i) { wr[i] = pr[i]; wz[i] = pz[i]; wn[i] = pn[i]; }
    }

    const float bn = bh[j + 512];   // r/z h2h biases folded into gi by gi_gemm

    float h_old = 0.f;
    if (q == 0) {
        h_old = (t_start == 0) ? hx[b * HDIM + j] : hstate[b * HDIM + j];
        hbuf[0][j] = (_Float16)h_old;
    }
    __syncthreads();

    const size_t STEP  = (size_t)BATCH * G3;
    const size_t OSTEP = (size_t)BATCH * HDIM;
    const _Float16* gp = gi + (size_t)b * G3 + j;
    float* outp = out + ((size_t)t_start * BATCH + b) * HDIM + j;

    // 1-deep prefetch of gi (current step), q==0 threads only
    float cr = 0.f, cz = 0.f, cn = 0.f;
    if (q == 0) {
        cr = (float)gp[0];
        cz = (float)gp[256];
        cn = (float)gp[512];
    }

    int p = 0;
    for (int tt = 0; tt < t_len; ++tt) {
        // Per-iteration pin: remat from global is illegal; 96 regs is small enough
        // that the allocator should hold (its observed keep threshold is ~85+).
        asm volatile("" : "+v"(wr[0]), "+v"(wr[1]), "+v"(wr[2]), "+v"(wr[3]),
                          "+v"(wr[4]), "+v"(wr[5]), "+v"(wr[6]), "+v"(wr[7]),
                          "+v"(wz[0]), "+v"(wz[1]), "+v"(wz[2]), "+v"(wz[3]),
                          "+v"(wz[4]), "+v"(wz[5]), "+v"(wz[6]), "+v"(wz[7]),
                          "+v"(wn[0]), "+v"(wn[1]), "+v"(wn[2]), "+v"(wn[3]),
                          "+v"(wn[4]), "+v"(wn[5]), "+v"(wn[6]), "+v"(wn[7]));

        const float ur = cr, uz = cz, un = cn;
        if (q == 0 && tt + 1 < t_len) {
            const _Float16* gn2 = gp + STEP;
            cr = (float)gn2[0];
            cz = (float)gn2[256];
            cn = (float)gn2[512];
        }
        gp += STEP;

        // Dot phase: 8 h-quads (LDS broadcast, conflict-free), 48 v_dot2 per thread.
        float ar = 0.f, az = 0.f, an = 0.f;
        const uint4v* hp = (const uint4v*)&hbuf[p][q * 64];
        #pragma unroll
        for (int i = 0; i < 8; ++i) {
            uint4v hv = hp[i];
            #pragma unroll
            for (int k = 0; k < 4; ++k) {
                ar = fdot2(u2h(wr[i][k]), u2h(hv[k]), ar);
                az = fdot2(u2h(wz[i][k]), u2h(hv[k]), az);
                an = fdot2(u2h(wn[i][k]), u2h(hv[k]), an);
            }
        }

        if (q) {
            psum[q - 1][0][j] = ar;
            psum[q - 1][1][j] = az;
            psum[q - 1][2][j] = an;
        }
        __syncthreads();
        if (q == 0) {
            float sr = ar + psum[0][0][j] + psum[1][0][j] + psum[2][0][j];
            float sz = az + psum[0][1][j] + psum[1][1][j] + psum[2][1][j];
            float sn = an + psum[0][2][j] + psum[1][2][j] + psum[2][2][j];
            float r = sigmoid_f(sr + ur);
            float z = sigmoid_f(sz + uz);
            float n = tanh_f(un + r * (sn + bn));
            float hnew = (1.f - z) * n + z * h_old;
            *outp = hnew;
            h_old = hnew;
            hbuf[p ^ 1][j] = (_Float16)hnew;
        }
        outp += OSTEP;
        __syncthreads();
        p ^= 1;
    }
    if (q == 0) hstate[b * HDIM + j] = h_old;
}

// ---------------------------------------------------------------- host
extern "C" void kernel_launch(void* const* d_in, const int* in_sizes, int n_in,
                              void* d_out, int out_size, void* d_ws, size_t ws_size,
                              hipStream_t stream) {
    const float* x     = (const float*)d_in[0];
    const float* hx    = (const float*)d_in[1];
    const float* x2h_w = (const float*)d_in[2];
    const float* h2h_w = (const float*)d_in[3];
    const float* x2h_b = (const float*)d_in[4];
    const float* h2h_b = (const float*)d_in[5];
    float* out = (float*)d_out;

    char* ws = (char*)d_ws;
    _Float16* wx16   = (_Float16*)ws;                    // 393216 B
    _Float16* wh16   = (_Float16*)(ws + 393216);         // 393216 B
    float*    hstate = (float*)(ws + 786432);            // 65536 B
    _Float16* gi     = (_Float16*)(ws + 851968);

    size_t gi_cap_elems = (ws_size > 851968) ? (ws_size - 851968) / 2 : 0;
    int CT = T_SEQ;
    while ((size_t)CT * BATCH * G3 > gi_cap_elems && CT > 64) CT >>= 1;

    cvt_init<<<768, 256, 0, stream>>>(x2h_w, h2h_w, hx, wx16, wh16, hstate,
                                      out + (size_t)T_SEQ * BATCH * HDIM);

    for (int t0 = 0; t0 < T_SEQ; t0 += CT) {
        int rows = CT * BATCH;
        gi_gemm<<<rows / 256, 256, 0, stream>>>(x, wx16, x2h_b, h2h_b, gi, t0 * BATCH);
        gru_rec<<<BATCH, 1024, 0, stream>>>(gi, wh16, h2h_b, hx, hstate, out, t0, CT);
    }
}

// Round 10
// 2517.872 us; speedup vs baseline: 4.5287x; 1.0933x over previous
//
#include <hip/hip_runtime.h>
#include <hip/hip_fp16.h>

// GRU: T=2048, B=64, I=H=256.  out = ([T,B,H] f32, initial hx)
//
//  1) cvt_init: f32->f16 weight copies into ws, h_state := hx, write hx tail of d_out.
//  2) gi_gemm:  gi = x @ x2h_w^T + (x2h_b + h2h_b[r,z]) via f16 MFMA, f16 in ws.
//  3) gru_rec:  64 WGs x 512 threads, K-split by 2; thread (half, j) owns the half-K
//               slices of h2h_w rows {j, j+256, j+512} = 48 uint4 = 192 VGPRs.
//               Residency mechanics (R3-R9 forensics):
//                 - 1024-thr WG caps VGPR at 128 (16 waves -> >=4/EU). Use 512 thr.
//                 - asm volatile("") pins get DELETED by LLVM -> remat -> L2-bound
//                   2.4 ms. Pin must contain a real instruction: "s_nop 0" with
//                   "+v" tied operands (non-deletable, non-rematerializable defs).
//                 - R4's spill trigger was the scheduler hoisting all 16 LDS h-quads
//                   (+64 regs). Ring-of-4 hv + sched_barrier(0) every 4 quads caps
//                   the spike at +16 while 48 dots/region hide ~120cyc LDS latency.
//               launch_bounds(512,1): RA budget 512 (VALU 256), steady ~238 regs,
//               actual occupancy 8 waves/CU (2/SIMD).

typedef _Float16 half2v __attribute__((ext_vector_type(2)));
typedef _Float16 half8  __attribute__((ext_vector_type(8)));
typedef float    f32x4  __attribute__((ext_vector_type(4)));
typedef unsigned int uint4v __attribute__((ext_vector_type(4)));

#define T_SEQ 2048
#define BATCH 64
#define HDIM  256
#define G3    768   // 3*H

__device__ __forceinline__ half2v u2h(unsigned int u) {
    union { unsigned int u; half2v h; } c; c.u = u; return c.h;
}

__device__ __forceinline__ float fdot2(half2v a, half2v b, float c) {
#if __has_builtin(__builtin_amdgcn_fdot2)
    return __builtin_amdgcn_fdot2(a, b, c, false);
#else
    return c + (float)a[0] * (float)b[0] + (float)a[1] * (float)b[1];
#endif
}

__device__ __forceinline__ float sigmoid_f(float x) {
    return 1.f / (1.f + __expf(-x));
}
__device__ __forceinline__ float tanh_f(float x) {
    float e = __expf(2.f * x);
    return 1.f - 2.f / (e + 1.f);
}

// ---------------------------------------------------------------- cvt_init
__global__ void cvt_init(const float* __restrict__ x2h_w, const float* __restrict__ h2h_w,
                         const float* __restrict__ hx,
                         _Float16* __restrict__ wx16, _Float16* __restrict__ wh16,
                         float* __restrict__ hstate, float* __restrict__ out_tail) {
    int i = blockIdx.x * 256 + threadIdx.x;
    if (i < G3 * HDIM) {
        wx16[i] = (_Float16)x2h_w[i];
        wh16[i] = (_Float16)h2h_w[i];
    }
    if (i < BATCH * HDIM) {
        float v = hx[i];
        hstate[i] = v;
        out_tail[i] = v;   // second output = INITIAL hx
    }
}

// ---------------------------------------------------------------- gi_gemm
// mfma_f32_16x16x32_f16: A lane holds A[row=l&15, k=(l>>4)*8+i];
// B lane holds B[k=(l>>4)*8+i, col=l&15]; D lane holds C[row=(l>>4)*4+r, col=l&15].
// Bias: x2h_b[col] + (col<512 ? h2h_b[col] : 0).
__global__ __launch_bounds__(256) void gi_gemm(const float* __restrict__ x,
                                               const _Float16* __restrict__ wx,
                                               const float* __restrict__ bx,
                                               const float* __restrict__ bh,
                                               _Float16* __restrict__ gi,
                                               int row_base) {
    const int lane  = threadIdx.x & 63;
    const int wave  = threadIdx.x >> 6;
    const int l15   = lane & 15;
    const int kslot = lane >> 4;               // 0..3
    const int row0  = row_base + blockIdx.x * 256 + wave * 64;

    half8 a[4][8];
    #pragma unroll
    for (int s = 0; s < 4; ++s) {
        const float* xr = x + (size_t)(row0 + s * 16 + l15) * HDIM + kslot * 8;
        #pragma unroll
        for (int kt = 0; kt < 8; ++kt) {
            float4 lo = *(const float4*)(xr + kt * 32);
            float4 hi = *(const float4*)(xr + kt * 32 + 4);
            half8 v;
            v[0] = (_Float16)lo.x; v[1] = (_Float16)lo.y; v[2] = (_Float16)lo.z; v[3] = (_Float16)lo.w;
            v[4] = (_Float16)hi.x; v[5] = (_Float16)hi.y; v[6] = (_Float16)hi.z; v[7] = (_Float16)hi.w;
            a[s][kt] = v;
        }
    }

    for (int nt = 0; nt < 48; ++nt) {
        half8 b[8];
        const _Float16* wr = wx + (size_t)(nt * 16 + l15) * HDIM + kslot * 8;
        #pragma unroll
        for (int kt = 0; kt < 8; ++kt) b[kt] = *(const half8*)(wr + kt * 32);
        const int   col  = nt * 16 + l15;
        float bias = bx[col];
        if (col < 512) bias += bh[col];
        #pragma unroll
        for (int s = 0; s < 4; ++s) {
            f32x4 acc = {0.f, 0.f, 0.f, 0.f};
            #pragma unroll
            for (int kt = 0; kt < 8; ++kt)
                acc = __builtin_amdgcn_mfma_f32_16x16x32_f16(a[s][kt], b[kt], acc, 0, 0, 0);
            #pragma unroll
            for (int r = 0; r < 4; ++r) {
                int rowl = (row0 - row_base) + s * 16 + kslot * 4 + r;
                gi[(size_t)rowl * G3 + col] = (_Float16)(acc[r] + bias);
            }
        }
    }
}

// 12 dots: one h-quad against the matching quads of all three gate rows.
#define DOTQ(HV, I)                                   \
    do {                                              \
        ar = fdot2(u2h(wr[I][0]), u2h(HV[0]), ar);    \
        az = fdot2(u2h(wz[I][0]), u2h(HV[0]), az);    \
        an = fdot2(u2h(wn[I][0]), u2h(HV[0]), an);    \
        ar = fdot2(u2h(wr[I][1]), u2h(HV[1]), ar);    \
        az = fdot2(u2h(wz[I][1]), u2h(HV[1]), az);    \
        an = fdot2(u2h(wn[I][1]), u2h(HV[1]), an);    \
        ar = fdot2(u2h(wr[I][2]), u2h(HV[2]), ar);    \
        az = fdot2(u2h(wz[I][2]), u2h(HV[2]), az);    \
        an = fdot2(u2h(wn[I][2]), u2h(HV[2]), an);    \
        ar = fdot2(u2h(wr[I][3]), u2h(HV[3]), ar);    \
        az = fdot2(u2h(wz[I][3]), u2h(HV[3]), az);    \
        an = fdot2(u2h(wn[I][3]), u2h(HV[3]), an);    \
    } while (0)

// ---------------------------------------------------------------- gru_rec
__global__ __launch_bounds__(512, 1) void gru_rec(const _Float16* __restrict__ gi,
                                                  const _Float16* __restrict__ wh,
                                                  const float* __restrict__ bh,
                                                  const float* __restrict__ hx,
                                                  float* __restrict__ hstate,
                                                  float* __restrict__ out,
                                                  int t_start, int t_len) {
    __shared__ __align__(16) _Float16 hbuf[2][HDIM];
    __shared__ float psum[3][HDIM];

    const int tid  = threadIdx.x;
    const int half = tid >> 8;            // 0: K in [0,128), 1: K in [128,256)
    const int j    = tid & 255;
    const int b    = blockIdx.x;

    // 3 half-rows -> 48 x uint4v = 192 VGPRs
    uint4v wr[16], wz[16], wn[16];
    {
        const uint4v* pr = (const uint4v*)(wh + (size_t)j * HDIM + half * 128);
        const uint4v* pz = (const uint4v*)(wh + (size_t)(j + 256) * HDIM + half * 128);
        const uint4v* pn = (const uint4v*)(wh + (size_t)(j + 512) * HDIM + half * 128);
        #pragma unroll
        for (int i = 0; i < 16; ++i) { wr[i] = pr[i]; wz[i] = pz[i]; wn[i] = pn[i]; }
    }

    const float bn = bh[j + 512];   // r/z h2h biases folded into gi by gi_gemm

    float h_old = 0.f;
    if (half == 0) {
        h_old = (t_start == 0) ? hx[b * HDIM + j] : hstate[b * HDIM + j];
        hbuf[0][j] = (_Float16)h_old;
    }
    __syncthreads();

    const size_t STEP  = (size_t)BATCH * G3;
    const size_t OSTEP = (size_t)BATCH * HDIM;
    const _Float16* gp = gi + (size_t)b * G3 + j;
    float* outp = out + ((size_t)t_start * BATCH + b) * HDIM + j;

    // 1-deep prefetch of gi (current step's values)
    float cr = 0.f, cz = 0.f, cn = 0.f;
    if (half == 0) {
        cr = (float)gp[0];
        cz = (float)gp[256];
        cn = (float)gp[512];
    }

    int p = 0;
    for (int tt = 0; tt < t_len; ++tt) {
        // REAL-instruction pins: non-deletable, defs non-rematerializable.
        asm volatile("s_nop 0" : "+v"(wr[0]), "+v"(wr[1]), "+v"(wr[2]), "+v"(wr[3]),
                                 "+v"(wr[4]), "+v"(wr[5]), "+v"(wr[6]), "+v"(wr[7]));
        asm volatile("s_nop 0" : "+v"(wr[8]), "+v"(wr[9]), "+v"(wr[10]), "+v"(wr[11]),
                                 "+v"(wr[12]), "+v"(wr[13]), "+v"(wr[14]), "+v"(wr[15]));
        asm volatile("s_nop 0" : "+v"(wz[0]), "+v"(wz[1]), "+v"(wz[2]), "+v"(wz[3]),
                                 "+v"(wz[4]), "+v"(wz[5]), "+v"(wz[6]), "+v"(wz[7]));
        asm volatile("s_nop 0" : "+v"(wz[8]), "+v"(wz[9]), "+v"(wz[10]), "+v"(wz[11]),
                                 "+v"(wz[12]), "+v"(wz[13]), "+v"(wz[14]), "+v"(wz[15]));
        asm volatile("s_nop 0" : "+v"(wn[0]), "+v"(wn[1]), "+v"(wn[2]), "+v"(wn[3]),
                                 "+v"(wn[4]), "+v"(wn[5]), "+v"(wn[6]), "+v"(wn[7]));
        asm volatile("s_nop 0" : "+v"(wn[8]), "+v"(wn[9]), "+v"(wn[10]), "+v"(wn[11]),
                                 "+v"(wn[12]), "+v"(wn[13]), "+v"(wn[14]), "+v"(wn[15]));

        const float ur = cr, uz = cz, un = cn;
        if (half == 0 && tt + 1 < t_len) {
            const _Float16* gn2 = gp + STEP;
            cr = (float)gn2[0];
            cz = (float)gn2[256];
            cn = (float)gn2[512];
        }
        gp += STEP;

        // Dot phase: hv ring of 4 (bounded +16 reg spike), sched_barrier per group
        // of 4 quads; 48 dots per region hide the LDS read latency.
        float ar = 0.f, az = 0.f, an = 0.f;
        const uint4v* hp = (const uint4v*)&hbuf[p][half * 128];
        uint4v h0 = hp[0], h1 = hp[1], h2 = hp[2], h3 = hp[3];

        DOTQ(h0, 0);  h0 = hp[4];
        DOTQ(h1, 1);  h1 = hp[5];
        DOTQ(h2, 2);  h2 = hp[6];
        DOTQ(h3, 3);  h3 = hp[7];
        __builtin_amdgcn_sched_barrier(0);
        DOTQ(h0, 4);  h0 = hp[8];
        DOTQ(h1, 5);  h1 = hp[9];
        DOTQ(h2, 6);  h2 = hp[10];
        DOTQ(h3, 7);  h3 = hp[11];
        __builtin_amdgcn_sched_barrier(0);
        DOTQ(h0, 8);  h0 = hp[12];
        DOTQ(h1, 9);  h1 = hp[13];
        DOTQ(h2, 10); h2 = hp[14];
        DOTQ(h3, 11); h3 = hp[15];
        __builtin_amdgcn_sched_barrier(0);
        DOTQ(h0, 12);
        DOTQ(h1, 13);
        DOTQ(h2, 14);
        DOTQ(h3, 15);

        if (half) { psum[0][j] = ar; psum[1][j] = az; psum[2][j] = an; }
        __syncthreads();
        if (!half) {
            float r = sigmoid_f(ar + psum[0][j] + ur);
            float z = sigmoid_f(az + psum[1][j] + uz);
            float n = tanh_f(un + r * (an + psum[2][j] + bn));
            float hnew = (1.f - z) * n + z * h_old;
            *outp = hnew;
            h_old = hnew;
            hbuf[p ^ 1][j] = (_Float16)hnew;
        }
        outp += OSTEP;
        __syncthreads();
        p ^= 1;
    }
    if (!half) hstate[b * HDIM + j] = h_old;
}

// ---------------------------------------------------------------- host
extern "C" void kernel_launch(void* const* d_in, const int* in_sizes, int n_in,
                              void* d_out, int out_size, void* d_ws, size_t ws_size,
                              hipStream_t stream) {
    const float* x     = (const float*)d_in[0];
    const float* hx    = (const float*)d_in[1];
    const float* x2h_w = (const float*)d_in[2];
    const float* h2h_w = (const float*)d_in[3];
    const float* x2h_b = (const float*)d_in[4];
    const float* h2h_b = (const float*)d_in[5];
    float* out = (float*)d_out;

    char* ws = (char*)d_ws;
    _Float16* wx16   = (_Float16*)ws;                    // 393216 B
    _Float16* wh16   = (_Float16*)(ws + 393216);         // 393216 B
    float*    hstate = (float*)(ws + 786432);            // 65536 B
    _Float16* gi     = (_Float16*)(ws + 851968);

    size_t gi_cap_elems = (ws_size > 851968) ? (ws_size - 851968) / 2 : 0;
    int CT = T_SEQ;
    while ((size_t)CT * BATCH * G3 > gi_cap_elems && CT > 64) CT >>= 1;

    cvt_init<<<768, 256, 0, stream>>>(x2h_w, h2h_w, hx, wx16, wh16, hstate,
                                      out + (size_t)T_SEQ * BATCH * HDIM);

    for (int t0 = 0; t0 < T_SEQ; t0 += CT) {
        int rows = CT * BATCH;
        gi_gemm<<<rows / 256, 256, 0, stream>>>(x, wx16, x2h_b, h2h_b, gi, t0 * BATCH);
        gru_rec<<<BATCH, 512, 0, stream>>>(gi, wh16, h2h_b, hx, hstate, out, t0, CT);
    }
}